// Round 1
// baseline (138.207 us; speedup 1.0000x reference)
//
#include <hip/hip_runtime.h>

#define BB 8
#define CCH 19
#define HH 512
#define WW 1024
#define HW (HH * WW)          // 524288
#define NPIX (BB * HW)        // 4194304
#define CHW (CCH * HW)
#define N4 (NPIX / 4)         // 1048576

struct SelState {
    unsigned num;
    unsigned b1, k1;
    unsigned b2, k2;
    unsigned tk_key;
};

__device__ __forceinline__ unsigned fkey(float x) {
    unsigned u = __float_as_uint(x);
    return (u & 0x80000000u) ? ~u : (u | 0x80000000u);
}

// ---- compute num from step (device-side; step is a device scalar) ----
__global__ void k_num(const int* __restrict__ step_p, SelState* st) {
    if (threadIdx.x == 0 && blockIdx.x == 0) {
        int step = step_p[0];
        double m = pow(0.99998, (double)step);
        double Kc = 0.15;
        double f = m > Kc ? m : Kc;
        double v = Kc * (double)BB * (double)HH * (double)WW * f;
        st->num = (unsigned)v;  // int() truncation, value is positive
    }
}

// ---- pass 1: per-pixel cross entropy, 4 pixels per thread (float4) ----
__global__ __launch_bounds__(256) void k_loss(const float* __restrict__ pred,
                                              const int* __restrict__ target,
                                              float* __restrict__ loss) {
    int i4 = blockIdx.x * 256 + threadIdx.x;
    int p0 = i4 << 2;
    int b = p0 >> 19;           // / HW
    int hw = p0 & (HW - 1);
    const float* base = pred + (size_t)b * CHW + hw;

    float4 v[CCH];
#pragma unroll
    for (int c = 0; c < CCH; ++c)
        v[c] = *reinterpret_cast<const float4*>(base + (size_t)c * HW);
    int4 tg = *reinterpret_cast<const int4*>(target + p0);

    float4 mx = v[0];
#pragma unroll
    for (int c = 1; c < CCH; ++c) {
        mx.x = fmaxf(mx.x, v[c].x);
        mx.y = fmaxf(mx.y, v[c].y);
        mx.z = fmaxf(mx.z, v[c].z);
        mx.w = fmaxf(mx.w, v[c].w);
    }
    float4 s = make_float4(0.f, 0.f, 0.f, 0.f);
    float4 xt = make_float4(0.f, 0.f, 0.f, 0.f);
#pragma unroll
    for (int c = 0; c < CCH; ++c) {
        s.x += __expf(v[c].x - mx.x);
        s.y += __expf(v[c].y - mx.y);
        s.z += __expf(v[c].z - mx.z);
        s.w += __expf(v[c].w - mx.w);
        xt.x = (tg.x == c) ? v[c].x : xt.x;
        xt.y = (tg.y == c) ? v[c].y : xt.y;
        xt.z = (tg.z == c) ? v[c].z : xt.z;
        xt.w = (tg.w == c) ? v[c].w : xt.w;
    }
    float4 o;
    o.x = __logf(s.x) + mx.x - xt.x;
    o.y = __logf(s.y) + mx.y - xt.y;
    o.z = __logf(s.z) + mx.z - xt.z;
    o.w = __logf(s.w) + mx.w - xt.w;
    *reinterpret_cast<float4*>(loss + p0) = o;
}

// ---- histogram passes (LDS-aggregated) ----
__global__ __launch_bounds__(256) void k_histA(const float* __restrict__ loss,
                                               unsigned* __restrict__ hist) {
    __shared__ unsigned h[2048];
    for (int i = threadIdx.x; i < 2048; i += 256) h[i] = 0;
    __syncthreads();
    int stride = gridDim.x * 256;
    for (int i4 = blockIdx.x * 256 + threadIdx.x; i4 < N4; i4 += stride) {
        float4 v = reinterpret_cast<const float4*>(loss)[i4];
        atomicAdd(&h[fkey(v.x) >> 21], 1u);
        atomicAdd(&h[fkey(v.y) >> 21], 1u);
        atomicAdd(&h[fkey(v.z) >> 21], 1u);
        atomicAdd(&h[fkey(v.w) >> 21], 1u);
    }
    __syncthreads();
    for (int i = threadIdx.x; i < 2048; i += 256) {
        unsigned c = h[i];
        if (c) atomicAdd(&hist[i], c);
    }
}

__global__ __launch_bounds__(256) void k_histB(const float* __restrict__ loss,
                                               const SelState* __restrict__ st,
                                               unsigned* __restrict__ hist) {
    __shared__ unsigned h[2048];
    for (int i = threadIdx.x; i < 2048; i += 256) h[i] = 0;
    __syncthreads();
    unsigned b1 = st->b1;
    int stride = gridDim.x * 256;
    for (int i4 = blockIdx.x * 256 + threadIdx.x; i4 < N4; i4 += stride) {
        float4 v = reinterpret_cast<const float4*>(loss)[i4];
        unsigned u;
        u = fkey(v.x); if ((u >> 21) == b1) atomicAdd(&h[(u >> 10) & 2047u], 1u);
        u = fkey(v.y); if ((u >> 21) == b1) atomicAdd(&h[(u >> 10) & 2047u], 1u);
        u = fkey(v.z); if ((u >> 21) == b1) atomicAdd(&h[(u >> 10) & 2047u], 1u);
        u = fkey(v.w); if ((u >> 21) == b1) atomicAdd(&h[(u >> 10) & 2047u], 1u);
    }
    __syncthreads();
    for (int i = threadIdx.x; i < 2048; i += 256) {
        unsigned c = h[i];
        if (c) atomicAdd(&hist[i], c);
    }
}

__global__ __launch_bounds__(256) void k_histC(const float* __restrict__ loss,
                                               const SelState* __restrict__ st,
                                               unsigned* __restrict__ hist) {
    __shared__ unsigned h[1024];
    for (int i = threadIdx.x; i < 1024; i += 256) h[i] = 0;
    __syncthreads();
    unsigned pref22 = (st->b1 << 11) | st->b2;
    int stride = gridDim.x * 256;
    for (int i4 = blockIdx.x * 256 + threadIdx.x; i4 < N4; i4 += stride) {
        float4 v = reinterpret_cast<const float4*>(loss)[i4];
        unsigned u;
        u = fkey(v.x); if ((u >> 10) == pref22) atomicAdd(&h[u & 1023u], 1u);
        u = fkey(v.y); if ((u >> 10) == pref22) atomicAdd(&h[u & 1023u], 1u);
        u = fkey(v.z); if ((u >> 10) == pref22) atomicAdd(&h[u & 1023u], 1u);
        u = fkey(v.w); if ((u >> 10) == pref22) atomicAdd(&h[u & 1023u], 1u);
    }
    __syncthreads();
    for (int i = threadIdx.x; i < 1024; i += 256) {
        unsigned c = h[i];
        if (c) atomicAdd(&hist[i], c);
    }
}

// ---- single-block suffix-scan to find the bin holding the k-th largest ----
template <int NBINS, int PASS>
__global__ __launch_bounds__(256) void k_scan(const unsigned* __restrict__ hist,
                                              SelState* st) {
    constexpr int PER = NBINS / 256;
    __shared__ unsigned chunk[256];
    int t = threadIdx.x;
    unsigned k = (PASS == 0) ? st->num : (PASS == 1 ? st->k1 : st->k2);

    unsigned local[PER];
    unsigned lsum = 0;
#pragma unroll
    for (int j = 0; j < PER; ++j) { local[j] = hist[t * PER + j]; lsum += local[j]; }
    chunk[t] = lsum;
    __syncthreads();
    // inclusive suffix scan (Hillis-Steele)
    for (int off = 1; off < 256; off <<= 1) {
        unsigned add = (t + off < 256) ? chunk[t + off] : 0u;
        __syncthreads();
        chunk[t] += add;
        __syncthreads();
    }
    unsigned cum = (t < 255) ? chunk[t + 1] : 0u;  // count strictly above my chunk
#pragma unroll
    for (int j = PER - 1; j >= 0; --j) {
        unsigned c = local[j];
        if (k > cum && k <= cum + c) {
            unsigned bin = (unsigned)(t * PER + j);
            unsigned krem = k - cum;
            if (PASS == 0) { st->b1 = bin; st->k1 = krem; }
            else if (PASS == 1) { st->b2 = bin; st->k2 = krem; }
            else { st->tk_key = (st->b1 << 21) | (st->b2 << 10) | bin; }
        }
        cum += c;
    }
}

// ---- final masked sum/count, deterministic two-stage reduction ----
__global__ __launch_bounds__(256) void k_final(const float* __restrict__ loss,
                                               const SelState* __restrict__ st,
                                               double* __restrict__ psum,
                                               unsigned* __restrict__ pcnt) {
    unsigned tk = st->tk_key;
    double sum = 0.0;
    unsigned cnt = 0;
    int stride = gridDim.x * 256;
    for (int i4 = blockIdx.x * 256 + threadIdx.x; i4 < N4; i4 += stride) {
        float4 v = reinterpret_cast<const float4*>(loss)[i4];
        if (fkey(v.x) >= tk) { sum += (double)v.x; cnt++; }
        if (fkey(v.y) >= tk) { sum += (double)v.y; cnt++; }
        if (fkey(v.z) >= tk) { sum += (double)v.z; cnt++; }
        if (fkey(v.w) >= tk) { sum += (double)v.w; cnt++; }
    }
#pragma unroll
    for (int off = 32; off >= 1; off >>= 1) {
        sum += __shfl_down(sum, off);
        cnt += __shfl_down(cnt, off);
    }
    __shared__ double wsum[4];
    __shared__ unsigned wcnt[4];
    int wid = threadIdx.x >> 6, lane = threadIdx.x & 63;
    if (lane == 0) { wsum[wid] = sum; wcnt[wid] = cnt; }
    __syncthreads();
    if (threadIdx.x == 0) {
        psum[blockIdx.x] = wsum[0] + wsum[1] + wsum[2] + wsum[3];
        pcnt[blockIdx.x] = wcnt[0] + wcnt[1] + wcnt[2] + wcnt[3];
    }
}

__global__ __launch_bounds__(256) void k_finalize(const double* __restrict__ psum,
                                                  const unsigned* __restrict__ pcnt,
                                                  float* __restrict__ out, int nblocks) {
    double s = 0.0;
    unsigned long long c = 0;
    for (int i = threadIdx.x; i < nblocks; i += 256) { s += psum[i]; c += pcnt[i]; }
#pragma unroll
    for (int off = 32; off >= 1; off >>= 1) {
        s += __shfl_down(s, off);
        c += __shfl_down(c, off);
    }
    __shared__ double wsum[4];
    __shared__ unsigned long long wcnt[4];
    int wid = threadIdx.x >> 6, lane = threadIdx.x & 63;
    if (lane == 0) { wsum[wid] = s; wcnt[wid] = c; }
    __syncthreads();
    if (threadIdx.x == 0) {
        double ts = wsum[0] + wsum[1] + wsum[2] + wsum[3];
        unsigned long long tc = wcnt[0] + wcnt[1] + wcnt[2] + wcnt[3];
        out[0] = (float)(ts / (double)tc);
    }
}

extern "C" void kernel_launch(void* const* d_in, const int* in_sizes, int n_in,
                              void* d_out, int out_size, void* d_ws, size_t ws_size,
                              hipStream_t stream) {
    const float* pred = (const float*)d_in[0];
    const int* target = (const int*)d_in[1];
    const int* step = (const int*)d_in[2];
    float* out = (float*)d_out;

    char* ws = (char*)d_ws;
    const size_t LOSS_BYTES = (size_t)NPIX * 4;        // 16 MiB
    float* loss = (float*)ws;
    unsigned* hist1 = (unsigned*)(ws + LOSS_BYTES);    // 2048
    unsigned* hist2 = hist1 + 2048;                    // 2048
    unsigned* hist3 = hist2 + 2048;                    // 1024
    SelState* st = (SelState*)(hist3 + 1024);          // 24 B -> pad
    double* psum = (double*)(ws + LOSS_BYTES + 20480 + 32);  // 1024 doubles
    unsigned* pcnt = (unsigned*)(psum + 1024);               // 1024 u32

    // zero the three histograms (state/partials are fully overwritten each call)
    hipMemsetAsync(hist1, 0, 20480, stream);

    k_num<<<1, 1, 0, stream>>>(step, st);
    k_loss<<<N4 / 256, 256, 0, stream>>>(pred, target, loss);
    k_histA<<<1024, 256, 0, stream>>>(loss, hist1);
    k_scan<2048, 0><<<1, 256, 0, stream>>>(hist1, st);
    k_histB<<<1024, 256, 0, stream>>>(loss, st, hist2);
    k_scan<2048, 1><<<1, 256, 0, stream>>>(hist2, st);
    k_histC<<<1024, 256, 0, stream>>>(loss, st, hist3);
    k_scan<1024, 2><<<1, 256, 0, stream>>>(hist3, st);
    k_final<<<1024, 256, 0, stream>>>(loss, st, psum, pcnt);
    k_finalize<<<1, 256, 0, stream>>>(psum, pcnt, out, 1024);
}